// Round 1
// baseline (1115.119 us; speedup 1.0000x reference)
//
#include <hip/hip_runtime.h>

#define T_SEQ 4096
#define H_NUM 12
#define HD    64
#define C_DIM 768
#define N_QKV 2304
#define HT    (T_SEQ * HD)   // per-head elements = 262144

// ---------------------------------------------------------------------------
// GEMM1: X[4096,768] @ W[768,2304] + b  -> scatter to qh/kh/vh [12][4096][64]
// 64x64 tile, Ktile=16, 256 threads, 4x4 micro-tile.
// ---------------------------------------------------------------------------
__global__ __launch_bounds__(256) void gemm_qkv_kernel(
    const float* __restrict__ X, const float* __restrict__ W,
    const float* __restrict__ bias,
    float* __restrict__ qh, float* __restrict__ kh, float* __restrict__ vh)
{
    __shared__ float As[16][68];   // As[kk][row]  (transposed A tile)
    __shared__ float Bs[16][68];   // Bs[kk][col]
    const int tid = threadIdx.x;
    const int tr = tid >> 4, tc = tid & 15;
    const int bx = blockIdx.x, by = blockIdx.y;
    const int row0 = by << 6, col0 = bx << 6;
    const int ar = tid >> 2, ak = (tid & 3) << 2;   // A-load: 1 float4/thread
    const int bk = tid >> 4, bc = (tid & 15) << 2;  // B-load: 1 float4/thread
    float acc[4][4] = {};
    for (int kt = 0; kt < C_DIM; kt += 16) {
        const float4 a = *(const float4*)(X + (size_t)(row0 + ar) * C_DIM + kt + ak);
        const float4 b = *(const float4*)(W + (size_t)(kt + bk) * N_QKV + col0 + bc);
        __syncthreads();
        As[ak + 0][ar] = a.x; As[ak + 1][ar] = a.y;
        As[ak + 2][ar] = a.z; As[ak + 3][ar] = a.w;
        *(float4*)&Bs[bk][bc] = b;
        __syncthreads();
        #pragma unroll
        for (int kk = 0; kk < 16; ++kk) {
            float a_[4], b_[4];
            *(float4*)a_ = *(float4*)&As[kk][tr << 2];
            *(float4*)b_ = *(float4*)&Bs[kk][tc << 2];
            #pragma unroll
            for (int i = 0; i < 4; ++i)
                #pragma unroll
                for (int j = 0; j < 4; ++j)
                    acc[i][j] = fmaf(a_[i], b_[j], acc[i][j]);
        }
    }
    // Each 64-col tile maps to exactly one (q/k/v, head): 2304/64=36, 12 per sec.
    const int sec = bx / 12;
    const int h   = bx % 12;
    float* dst = (sec == 0) ? qh : ((sec == 1) ? kh : vh);
    #pragma unroll
    for (int i = 0; i < 4; ++i) {
        const int t = row0 + (tr << 2) + i;
        const int d = tc << 2;
        float4 o;
        o.x = acc[i][0] + bias[col0 + d + 0];
        o.y = acc[i][1] + bias[col0 + d + 1];
        o.z = acc[i][2] + bias[col0 + d + 2];
        o.w = acc[i][3] + bias[col0 + d + 3];
        *(float4*)(dst + (size_t)h * HT + (size_t)t * HD + d) = o;
    }
}

// ---------------------------------------------------------------------------
// In-place L2 normalize rows of 64 for qh and kh. One 64-lane wave per row.
// ---------------------------------------------------------------------------
__global__ __launch_bounds__(256) void l2norm_kernel(
    float* __restrict__ qh, float* __restrict__ kh)
{
    const int row = blockIdx.x * 4 + (threadIdx.x >> 6);
    const int d   = threadIdx.x & 63;
    float* base = qh;
    int r = row;
    if (row >= H_NUM * T_SEQ) { base = kh; r = row - H_NUM * T_SEQ; }
    float v = base[(size_t)r * HD + d];
    float s = v * v;
    #pragma unroll
    for (int m = 32; m >= 1; m >>= 1) s += __shfl_xor(s, m, 64);
    const float n = sqrtf(s);
    base[(size_t)r * HD + d] = v / fmaxf(n, 1e-12f);
}

// ---------------------------------------------------------------------------
// Fused attention: per (head, 64-row q tile), walk k-tiles in order.
//   S = Qn Kn^T (64x64), per-row running cumsum -> att = S / max(cum,1e-6),
//   Y += att @ V.  K and V share one LDS buffer (V loaded after S compute).
// ---------------------------------------------------------------------------
__global__ __launch_bounds__(256) void attn_kernel(
    const float* __restrict__ qh, const float* __restrict__ kh,
    const float* __restrict__ vh, float* __restrict__ ylin)
{
    __shared__ float Qs[64][68];   // [d][r]  transposed Q tile
    __shared__ float KV[64][68];   // K phase: [d][c]; V phase: [c][d]
    __shared__ float Ss[64][68];   // scores / att, [r][c]
    const int tid = threadIdx.x;
    const int tr = tid >> 4, tc = tid & 15;
    const int h  = blockIdx.y, qt = blockIdx.x;
    const float* qb = qh + (size_t)h * HT + (size_t)qt * 64 * HD;
    const float* kb = kh + (size_t)h * HT;
    const float* vb = vh + (size_t)h * HT;

    // load Q tile transposed (once)
    #pragma unroll
    for (int i = 0; i < 4; ++i) {
        const int f4 = tid + i * 256;
        const int r = f4 >> 4, d0 = (f4 & 15) << 2;
        const float4 a = *(const float4*)(qb + (size_t)r * HD + d0);
        Qs[d0 + 0][r] = a.x; Qs[d0 + 1][r] = a.y;
        Qs[d0 + 2][r] = a.z; Qs[d0 + 3][r] = a.w;
    }

    float acc[4][4] = {};
    float carry = 0.0f;   // per-row cumsum carry (valid for tid < 64)

    for (int kt = 0; kt < T_SEQ / 64; ++kt) {
        const float* kbt = kb + (size_t)kt * 64 * HD;
        const float* vbt = vb + (size_t)kt * 64 * HD;
        // prefetch K tile to registers
        float4 kreg[4];
        #pragma unroll
        for (int i = 0; i < 4; ++i) {
            const int f4 = tid + i * 256;
            kreg[i] = *(const float4*)(kbt + (size_t)(f4 >> 4) * HD + ((f4 & 15) << 2));
        }
        __syncthreads();                 // (A) prev-iter AV done with KV/Ss; Qs visible
        #pragma unroll
        for (int i = 0; i < 4; ++i) {
            const int f4 = tid + i * 256;
            const int c = f4 >> 4, d0 = (f4 & 15) << 2;
            KV[d0 + 0][c] = kreg[i].x; KV[d0 + 1][c] = kreg[i].y;
            KV[d0 + 2][c] = kreg[i].z; KV[d0 + 3][c] = kreg[i].w;
        }
        __syncthreads();                 // (B) K tile visible

        // S = Q K^T : thread computes 4x4 at (tr*4, tc*4)
        float s[4][4] = {};
        #pragma unroll 4
        for (int d = 0; d < 64; ++d) {
            float a_[4], b_[4];
            *(float4*)a_ = *(float4*)&Qs[d][tr << 2];
            *(float4*)b_ = *(float4*)&KV[d][tc << 2];
            #pragma unroll
            for (int i = 0; i < 4; ++i)
                #pragma unroll
                for (int j = 0; j < 4; ++j)
                    s[i][j] = fmaf(a_[i], b_[j], s[i][j]);
        }
        // prefetch V tile to registers
        float4 vreg[4];
        #pragma unroll
        for (int i = 0; i < 4; ++i) {
            const int f4 = tid + i * 256;
            vreg[i] = *(const float4*)(vbt + (size_t)(f4 >> 4) * HD + ((f4 & 15) << 2));
        }
        __syncthreads();                 // (C) all done reading K from KV
        #pragma unroll
        for (int i = 0; i < 4; ++i)
            *(float4*)&Ss[(tr << 2) + i][tc << 2] =
                make_float4(s[i][0], s[i][1], s[i][2], s[i][3]);
        #pragma unroll
        for (int i = 0; i < 4; ++i) {
            const int f4 = tid + i * 256;
            *(float4*)&KV[f4 >> 4][(f4 & 15) << 2] = vreg[i];
        }
        __syncthreads();                 // (D) Ss + V visible

        // sequential per-row scan: cumsum -> att = num * rcp(max(cum, 1e-6))
        if (tid < 64) {
            float cum = carry;
            #pragma unroll
            for (int c0 = 0; c0 < 64; c0 += 4) {
                float n_[4], o_[4];
                *(float4*)n_ = *(float4*)&Ss[tid][c0];
                #pragma unroll
                for (int u = 0; u < 4; ++u) {
                    cum += n_[u];
                    const float dn = fmaxf(cum, 1e-6f);
                    o_[u] = n_[u] * __builtin_amdgcn_rcpf(dn);
                }
                *(float4*)&Ss[tid][c0] = *(float4*)o_;
            }
            carry = cum;
        }
        __syncthreads();                 // (E) att ready

        // Y += att @ V : 4 rows x 4 dims per thread, c-unrolled by 4
        #pragma unroll 1
        for (int c0 = 0; c0 < 64; c0 += 4) {
            float a0_[4], a1_[4], a2_[4], a3_[4];
            *(float4*)a0_ = *(float4*)&Ss[(tr << 2) + 0][c0];
            *(float4*)a1_ = *(float4*)&Ss[(tr << 2) + 1][c0];
            *(float4*)a2_ = *(float4*)&Ss[(tr << 2) + 2][c0];
            *(float4*)a3_ = *(float4*)&Ss[(tr << 2) + 3][c0];
            float v_[4][4];
            #pragma unroll
            for (int u = 0; u < 4; ++u)
                *(float4*)v_[u] = *(float4*)&KV[c0 + u][tc << 2];
            #pragma unroll
            for (int u = 0; u < 4; ++u) {
                #pragma unroll
                for (int j = 0; j < 4; ++j) {
                    acc[0][j] = fmaf(a0_[u], v_[u][j], acc[0][j]);
                    acc[1][j] = fmaf(a1_[u], v_[u][j], acc[1][j]);
                    acc[2][j] = fmaf(a2_[u], v_[u][j], acc[2][j]);
                    acc[3][j] = fmaf(a3_[u], v_[u][j], acc[3][j]);
                }
            }
        }
    }
    // epilogue: ylin[t, h*64 + dv]
    #pragma unroll
    for (int i = 0; i < 4; ++i) {
        const int t = qt * 64 + (tr << 2) + i;
        *(float4*)(ylin + (size_t)t * C_DIM + h * HD + (tc << 2)) =
            make_float4(acc[i][0], acc[i][1], acc[i][2], acc[i][3]);
    }
}

// ---------------------------------------------------------------------------
// Proj GEMM: ylin[4096,768] @ Wp[768,768] + bp -> out[4096,768]
// ---------------------------------------------------------------------------
__global__ __launch_bounds__(256) void gemm_proj_kernel(
    const float* __restrict__ A, const float* __restrict__ W,
    const float* __restrict__ bias, float* __restrict__ out)
{
    __shared__ float As[16][68];
    __shared__ float Bs[16][68];
    const int tid = threadIdx.x;
    const int tr = tid >> 4, tc = tid & 15;
    const int bx = blockIdx.x, by = blockIdx.y;
    const int row0 = by << 6, col0 = bx << 6;
    const int ar = tid >> 2, ak = (tid & 3) << 2;
    const int bk = tid >> 4, bc = (tid & 15) << 2;
    float acc[4][4] = {};
    for (int kt = 0; kt < C_DIM; kt += 16) {
        const float4 a = *(const float4*)(A + (size_t)(row0 + ar) * C_DIM + kt + ak);
        const float4 b = *(const float4*)(W + (size_t)(kt + bk) * C_DIM + col0 + bc);
        __syncthreads();
        As[ak + 0][ar] = a.x; As[ak + 1][ar] = a.y;
        As[ak + 2][ar] = a.z; As[ak + 3][ar] = a.w;
        *(float4*)&Bs[bk][bc] = b;
        __syncthreads();
        #pragma unroll
        for (int kk = 0; kk < 16; ++kk) {
            float a_[4], b_[4];
            *(float4*)a_ = *(float4*)&As[kk][tr << 2];
            *(float4*)b_ = *(float4*)&Bs[kk][tc << 2];
            #pragma unroll
            for (int i = 0; i < 4; ++i)
                #pragma unroll
                for (int j = 0; j < 4; ++j)
                    acc[i][j] = fmaf(a_[i], b_[j], acc[i][j]);
        }
    }
    #pragma unroll
    for (int i = 0; i < 4; ++i) {
        const int t = row0 + (tr << 2) + i;
        const int d = tc << 2;
        float4 o;
        o.x = acc[i][0] + bias[col0 + d + 0];
        o.y = acc[i][1] + bias[col0 + d + 1];
        o.z = acc[i][2] + bias[col0 + d + 2];
        o.w = acc[i][3] + bias[col0 + d + 3];
        *(float4*)(out + (size_t)t * C_DIM + col0 + d) = o;
    }
}

extern "C" void kernel_launch(void* const* d_in, const int* in_sizes, int n_in,
                              void* d_out, int out_size, void* d_ws, size_t ws_size,
                              hipStream_t stream)
{
    const float* x      = (const float*)d_in[0];
    const float* w_attn = (const float*)d_in[1];
    const float* b_attn = (const float*)d_in[2];
    const float* w_proj = (const float*)d_in[3];
    const float* b_proj = (const float*)d_in[4];
    float* out = (float*)d_out;

    const size_t per = (size_t)H_NUM * HT;   // 3,145,728 floats
    float* ws   = (float*)d_ws;
    float* qh   = ws;
    float* kh   = ws + per;
    float* vh   = ws + 2 * per;
    float* ylin = ws + 3 * per;              // total 50.3 MB

    gemm_qkv_kernel<<<dim3(N_QKV / 64, T_SEQ / 64), 256, 0, stream>>>(
        x, w_attn, b_attn, qh, kh, vh);
    l2norm_kernel<<<(2 * H_NUM * T_SEQ) / 4, 256, 0, stream>>>(qh, kh);
    attn_kernel<<<dim3(T_SEQ / 64, H_NUM), 256, 0, stream>>>(qh, kh, vh, ylin);
    gemm_proj_kernel<<<dim3(C_DIM / 64, T_SEQ / 64), 256, 0, stream>>>(
        ylin, w_proj, b_proj, out);
}

// Round 2
// 925.651 us; speedup vs baseline: 1.2047x; 1.2047x over previous
//
#include <hip/hip_runtime.h>

#define T_SEQ 4096
#define H_NUM 12
#define HD    64
#define C_DIM 768
#define N_QKV 2304
#define HT    (T_SEQ * HD)   // per-head elements = 262144

typedef float    f32x4  __attribute__((ext_vector_type(4)));
typedef _Float16 half8  __attribute__((ext_vector_type(8)));
typedef _Float16 half4  __attribute__((ext_vector_type(4)));
typedef _Float16 half2v __attribute__((ext_vector_type(2)));

// ---------------------------------------------------------------------------
// GEMM1: X[4096,768] @ W[768,2304] + b -> q,k (fp32, l2-normalized), v (f16)
// 64x64 tile, Ktile=16, 256 threads, 4x4 micro-tile. Bias + L2 norm fused:
// the 64-col tile spans exactly one head's dim, so row-norm = 16-lane shuffle.
// ---------------------------------------------------------------------------
__global__ __launch_bounds__(256) void gemm_qkv_kernel(
    const float* __restrict__ X, const float* __restrict__ W,
    const float* __restrict__ bias,
    float* __restrict__ qh, float* __restrict__ kh, _Float16* __restrict__ vh)
{
    __shared__ float As[16][68];   // As[kk][row]  (transposed A tile)
    __shared__ float Bs[16][68];   // Bs[kk][col]
    const int tid = threadIdx.x;
    const int tr = tid >> 4, tc = tid & 15;
    const int bx = blockIdx.x, by = blockIdx.y;
    const int row0 = by << 6, col0 = bx << 6;
    const int ar = tid >> 2, ak = (tid & 3) << 2;
    const int bk = tid >> 4, bc = (tid & 15) << 2;
    float acc[4][4] = {};
    for (int kt = 0; kt < C_DIM; kt += 16) {
        const float4 a = *(const float4*)(X + (size_t)(row0 + ar) * C_DIM + kt + ak);
        const float4 b = *(const float4*)(W + (size_t)(kt + bk) * N_QKV + col0 + bc);
        __syncthreads();
        As[ak + 0][ar] = a.x; As[ak + 1][ar] = a.y;
        As[ak + 2][ar] = a.z; As[ak + 3][ar] = a.w;
        *(float4*)&Bs[bk][bc] = b;
        __syncthreads();
        #pragma unroll
        for (int kk = 0; kk < 16; ++kk) {
            float a_[4], b_[4];
            *(float4*)a_ = *(float4*)&As[kk][tr << 2];
            *(float4*)b_ = *(float4*)&Bs[kk][tc << 2];
            #pragma unroll
            for (int i = 0; i < 4; ++i)
                #pragma unroll
                for (int j = 0; j < 4; ++j)
                    acc[i][j] = fmaf(a_[i], b_[j], acc[i][j]);
        }
    }
    const int sec = bx / 12;
    const int h   = bx % 12;
    float o[4][4];
    #pragma unroll
    for (int i = 0; i < 4; ++i)
        #pragma unroll
        for (int j = 0; j < 4; ++j)
            o[i][j] = acc[i][j] + bias[col0 + (tc << 2) + j];

    if (sec < 2) {
        float* dst = (sec == 0) ? qh : kh;
        #pragma unroll
        for (int i = 0; i < 4; ++i) {
            float ss = o[i][0]*o[i][0] + o[i][1]*o[i][1]
                     + o[i][2]*o[i][2] + o[i][3]*o[i][3];
            #pragma unroll
            for (int m = 1; m < 16; m <<= 1) ss += __shfl_xor(ss, m, 16);
            const float invn = 1.0f / fmaxf(sqrtf(ss), 1e-12f);
            const int t = row0 + (tr << 2) + i;
            float4 ov;
            ov.x = o[i][0]*invn; ov.y = o[i][1]*invn;
            ov.z = o[i][2]*invn; ov.w = o[i][3]*invn;
            *(float4*)(dst + (size_t)h * HT + (size_t)t * HD + (tc << 2)) = ov;
        }
    } else {
        #pragma unroll
        for (int i = 0; i < 4; ++i) {
            const int t = row0 + (tr << 2) + i;
            half4 hv = {(_Float16)o[i][0], (_Float16)o[i][1],
                        (_Float16)o[i][2], (_Float16)o[i][3]};
            *(half4*)(vh + (size_t)h * HT + (size_t)t * HD + (tc << 2)) = hv;
        }
    }
}

// ---------------------------------------------------------------------------
// Fused attention. 128 threads/block (2 waves), 768 blocks = exactly 3/CU.
//   S = Qn Kn^T fp32 VALU, 8x4 micro-tile (rows tr*8.., cols tc*4..)
//   cumsum: in-register segmented shuffle scan across 16 lanes
//   att scaled 2^-5 -> f16 -> LDS; AV via mfma_f32_16x16x32_f16
//   y written to ylin as f16 scaled 2^-12 (feeds f16 proj GEMM)
// ---------------------------------------------------------------------------
__global__ __launch_bounds__(128) void attn_kernel(
    const float* __restrict__ qh, const float* __restrict__ kh,
    const _Float16* __restrict__ vh, _Float16* __restrict__ ylin)
{
    __shared__ float    Qs[64][68];   // [d][r]
    __shared__ float    Ks[64][68];   // [d][k]
    __shared__ _Float16 Ps[64][72];   // att [r][k], scaled 2^-5
    __shared__ _Float16 Vt[64][72];   // [dv][k]

    const int tid = threadIdx.x;
    const int tc = tid & 15, tr = tid >> 4;       // S micro: rows tr*8..+7, cols tc*4..+3
    const int h = blockIdx.y, qt = blockIdx.x;
    const float*    qb = qh + (size_t)h * HT + (size_t)qt * 64 * HD;
    const float*    kb = kh + (size_t)h * HT;
    const _Float16* vb = vh + (size_t)h * HT;

    // ---- stage Q transposed (once): pair-loads -> float2 writes (2-way-free)
    {
        const int d0 = (tid & 15) << 2;
        const int pv = tid >> 4;
        #pragma unroll
        for (int i = 0; i < 4; ++i) {
            const int p = pv + 8 * i;
            const float4 a = *(const float4*)(qb + (size_t)(2*p)   * HD + d0);
            const float4 b = *(const float4*)(qb + (size_t)(2*p+1) * HD + d0);
            const float av[4] = {a.x, a.y, a.z, a.w};
            const float bv[4] = {b.x, b.y, b.z, b.w};
            #pragma unroll
            for (int u = 0; u < 4; ++u)
                *(float2*)&Qs[d0 + u][2*p] = make_float2(av[u], bv[u]);
        }
    }

    float carry[8];
    #pragma unroll
    for (int i = 0; i < 8; ++i) carry[i] = 0.0f;
    f32x4 yacc[2][4];
    #pragma unroll
    for (int rt = 0; rt < 2; ++rt)
        #pragma unroll
        for (int ct = 0; ct < 4; ++ct)
            yacc[rt][ct] = (f32x4){0.f, 0.f, 0.f, 0.f};

    // prefetch registers for K (fp32 pairs) and V (f16 rows)
    const int kd0 = (tid & 15) << 2, kpv = tid >> 4;
    const int vd0 = (tid & 7) << 3,  vpv = tid >> 3;
    float4 kra[4], krb[4];
    half8  vra[2], vrb[2];
    auto load_kv = [&](int kt) {
        const float*    kbt = kb + (size_t)kt * 64 * HD;
        const _Float16* vbt = vb + (size_t)kt * 64 * HD;
        #pragma unroll
        for (int i = 0; i < 4; ++i) {
            const int k = 2 * (kpv + 8 * i);
            kra[i] = *(const float4*)(kbt + (size_t)k     * HD + kd0);
            krb[i] = *(const float4*)(kbt + (size_t)(k+1) * HD + kd0);
        }
        #pragma unroll
        for (int i = 0; i < 2; ++i) {
            const int k = 2 * (vpv + 16 * i);
            vra[i] = *(const half8*)(vbt + (size_t)k     * HD + vd0);
            vrb[i] = *(const half8*)(vbt + (size_t)(k+1) * HD + vd0);
        }
    };
    load_kv(0);

    const int lane = tid & 63, wv = tid >> 6;
    const int fm = lane & 15, fg = lane >> 4;

    for (int kt = 0; kt < T_SEQ / 64; ++kt) {
        __syncthreads();   // (A) prev S done with Ks, prev AV done with Vt/Ps
        #pragma unroll
        for (int i = 0; i < 4; ++i) {
            const int p = kpv + 8 * i;
            const float av[4] = {kra[i].x, kra[i].y, kra[i].z, kra[i].w};
            const float bv[4] = {krb[i].x, krb[i].y, krb[i].z, krb[i].w};
            #pragma unroll
            for (int u = 0; u < 4; ++u)
                *(float2*)&Ks[kd0 + u][2*p] = make_float2(av[u], bv[u]);
        }
        #pragma unroll
        for (int i = 0; i < 2; ++i) {
            const int p = vpv + 16 * i;
            #pragma unroll
            for (int u = 0; u < 8; ++u) {
                half2v pk = {vra[i][u], vrb[i][u]};
                *(half2v*)&Vt[vd0 + u][2*p] = pk;
            }
        }
        __syncthreads();   // (B) K/V tiles visible
        if (kt + 1 < T_SEQ / 64) load_kv(kt + 1);  // overlap next loads w/ compute

        // ---- S = Q K^T, 8x4 per thread
        float s[8][4] = {};
        #pragma unroll 2
        for (int d = 0; d < 64; ++d) {
            const f32x4 a0 = *(f32x4*)&Qs[d][tr << 3];
            const f32x4 a1 = *(f32x4*)&Qs[d][(tr << 3) + 4];
            const f32x4 b  = *(f32x4*)&Ks[d][tc << 2];
            #pragma unroll
            for (int i = 0; i < 4; ++i)
                #pragma unroll
                for (int j = 0; j < 4; ++j) {
                    s[i][j]     = fmaf(a0[i], b[j], s[i][j]);
                    s[i + 4][j] = fmaf(a1[i], b[j], s[i + 4][j]);
                }
        }

        // ---- register scan (inclusive cumsum over k) + att -> f16 -> Ps
        #pragma unroll
        for (int i = 0; i < 8; ++i) {
            const float p0 = s[i][0];
            const float p1 = p0 + s[i][1];
            const float p2 = p1 + s[i][2];
            const float tot = p2 + s[i][3];
            float inc = tot;
            #pragma unroll
            for (int dlt = 1; dlt < 16; dlt <<= 1) {
                const float n = __shfl_up(inc, dlt, 16);
                if (tc >= dlt) inc += n;
            }
            const float base = carry[i] + (inc - tot);
            const float a0 = s[i][0] * __builtin_amdgcn_rcpf(fmaxf(base + p0,  1e-6f));
            const float a1 = s[i][1] * __builtin_amdgcn_rcpf(fmaxf(base + p1,  1e-6f));
            const float a2 = s[i][2] * __builtin_amdgcn_rcpf(fmaxf(base + p2,  1e-6f));
            const float a3 = s[i][3] * __builtin_amdgcn_rcpf(fmaxf(base + tot, 1e-6f));
            carry[i] += __shfl(inc, 15, 16);   // full row total
            half4 o = {(_Float16)(a0 * 0.03125f), (_Float16)(a1 * 0.03125f),
                       (_Float16)(a2 * 0.03125f), (_Float16)(a3 * 0.03125f)};
            *(half4*)&Ps[(tr << 3) + i][tc << 2] = o;
        }
        __syncthreads();   // (C) att + V ready

        // ---- Y += att @ V via f16 MFMA. wave wv: row-tiles {2wv, 2wv+1}
        #pragma unroll
        for (int kc = 0; kc < 2; ++kc) {
            half8 af[2], bf[4];
            #pragma unroll
            for (int rt = 0; rt < 2; ++rt)
                af[rt] = *(half8*)&Ps[(2*wv + rt) * 16 + fm][kc * 32 + fg * 8];
            #pragma unroll
            for (int ct = 0; ct < 4; ++ct)
                bf[ct] = *(half8*)&Vt[ct * 16 + fm][kc * 32 + fg * 8];
            #pragma unroll
            for (int rt = 0; rt < 2; ++rt)
                #pragma unroll
                for (int ct = 0; ct < 4; ++ct)
                    yacc[rt][ct] = __builtin_amdgcn_mfma_f32_16x16x32_f16(
                        af[rt], bf[ct], yacc[rt][ct], 0, 0, 0);
        }
    }

    // epilogue: ylin f16 = y * 2^-12  (acc holds y * 2^-5 -> scale 2^-7)
    #pragma unroll
    for (int rt = 0; rt < 2; ++rt)
        #pragma unroll
        for (int ct = 0; ct < 4; ++ct)
            #pragma unroll
            for (int r = 0; r < 4; ++r) {
                const int t  = qt * 64 + (2*wv + rt) * 16 + fg * 4 + r;
                const int dv = ct * 16 + fm;
                ylin[(size_t)t * C_DIM + h * HD + dv] =
                    (_Float16)(yacc[rt][ct][r] * 0.0078125f);
            }
}

// ---------------------------------------------------------------------------
// Proj GEMM via f16 MFMA: ylin(f16, *2^-12)[4096,768] @ Wp[768,768] -> out fp32
// 256 threads, 64x64 tile, K-chunk 64. out = acc*2^12 + bias.
// ---------------------------------------------------------------------------
__global__ __launch_bounds__(256) void gemm_proj_kernel(
    const _Float16* __restrict__ A, const float* __restrict__ W,
    const float* __restrict__ bias, float* __restrict__ out)
{
    __shared__ _Float16 As[64][72];   // [m][k]
    __shared__ _Float16 Bt[64][72];   // [n][k]
    const int tid = threadIdx.x;
    const int w = tid >> 6, lane = tid & 63;
    const int m = lane & 15, g = lane >> 4;
    const int row0 = blockIdx.x << 6, col0 = blockIdx.y << 6;
    const int ar = tid >> 3, ac8 = (tid & 7) << 3;
    const int bn0 = (tid & 15) << 2, bpv = tid >> 4;
    f32x4 acc[4];
    #pragma unroll
    for (int ct = 0; ct < 4; ++ct) acc[ct] = (f32x4){0.f, 0.f, 0.f, 0.f};

    for (int kt = 0; kt < C_DIM; kt += 64) {
        half8 av0 = *(const half8*)(A + (size_t)(row0 + ar)      * C_DIM + kt + ac8);
        half8 av1 = *(const half8*)(A + (size_t)(row0 + ar + 32) * C_DIM + kt + ac8);
        float4 w0[2], w1[2];
        #pragma unroll
        for (int i = 0; i < 2; ++i) {
            const int k = kt + 2 * (bpv + 16 * i);
            w0[i] = *(const float4*)(W + (size_t)k       * C_DIM + col0 + bn0);
            w1[i] = *(const float4*)(W + (size_t)(k + 1) * C_DIM + col0 + bn0);
        }
        __syncthreads();
        *(half8*)&As[ar][ac8]      = av0;
        *(half8*)&As[ar + 32][ac8] = av1;
        #pragma unroll
        for (int i = 0; i < 2; ++i) {
            const int p = bpv + 16 * i;
            const float a_[4] = {w0[i].x, w0[i].y, w0[i].z, w0[i].w};
            const float b_[4] = {w1[i].x, w1[i].y, w1[i].z, w1[i].w};
            #pragma unroll
            for (int u = 0; u < 4; ++u) {
                half2v pk = {(_Float16)a_[u], (_Float16)b_[u]};
                *(half2v*)&Bt[bn0 + u][2*p] = pk;
            }
        }
        __syncthreads();
        #pragma unroll
        for (int kc = 0; kc < 2; ++kc) {
            const half8 a = *(half8*)&As[w * 16 + m][kc * 32 + g * 8];
            #pragma unroll
            for (int ct = 0; ct < 4; ++ct) {
                const half8 b = *(half8*)&Bt[ct * 16 + m][kc * 32 + g * 8];
                acc[ct] = __builtin_amdgcn_mfma_f32_16x16x32_f16(a, b, acc[ct], 0, 0, 0);
            }
        }
    }
    #pragma unroll
    for (int ct = 0; ct < 4; ++ct)
        #pragma unroll
        for (int r = 0; r < 4; ++r) {
            const int t = row0 + w * 16 + g * 4 + r;
            const int n = col0 + ct * 16 + m;
            out[(size_t)t * C_DIM + n] = acc[ct][r] * 4096.0f + bias[n];
        }
}

extern "C" void kernel_launch(void* const* d_in, const int* in_sizes, int n_in,
                              void* d_out, int out_size, void* d_ws, size_t ws_size,
                              hipStream_t stream)
{
    const float* x      = (const float*)d_in[0];
    const float* w_attn = (const float*)d_in[1];
    const float* b_attn = (const float*)d_in[2];
    const float* w_proj = (const float*)d_in[3];
    const float* b_proj = (const float*)d_in[4];
    float* out = (float*)d_out;

    const size_t per = (size_t)H_NUM * HT;        // 3,145,728
    float* ws = (float*)d_ws;
    float*     qh   = ws;
    float*     kh   = ws + per;
    _Float16*  vh   = (_Float16*)(ws + 2 * per);
    _Float16*  ylin = vh + per;                   // total ~37.7 MB

    gemm_qkv_kernel<<<dim3(N_QKV / 64, T_SEQ / 64), 256, 0, stream>>>(
        x, w_attn, b_attn, qh, kh, vh);
    attn_kernel<<<dim3(T_SEQ / 64, H_NUM), 128, 0, stream>>>(qh, kh, vh, ylin);
    gemm_proj_kernel<<<dim3(T_SEQ / 64, C_DIM / 64), 256, 0, stream>>>(
        ylin, w_proj, b_proj, out);
}

// Round 3
// 794.205 us; speedup vs baseline: 1.4041x; 1.1655x over previous
//
#include <hip/hip_runtime.h>

#define T_SEQ 4096
#define H_NUM 12
#define HD    64
#define C_DIM 768
#define N_QKV 2304
#define HT    (T_SEQ * HD)   // per-head elements = 262144

typedef float    f32x4  __attribute__((ext_vector_type(4)));
typedef _Float16 half8  __attribute__((ext_vector_type(8)));
typedef _Float16 half4  __attribute__((ext_vector_type(4)));

// ---------------------------------------------------------------------------
// GEMM1: X[4096,768] @ W[768,2304] + b ->
//   q,k: l2-normalized, split-f16 planes  qhi/qlo/khi/klo [h][t][d]
//   v:   f16 transposed                   vt [h][dv][t]
// 64x64 tile, Ktile=16, 256 threads, 4x4 micro-tile (fp32 mainloop).
// ---------------------------------------------------------------------------
__global__ __launch_bounds__(256) void gemm_qkv_kernel(
    const float* __restrict__ X, const float* __restrict__ W,
    const float* __restrict__ bias,
    _Float16* __restrict__ qhi, _Float16* __restrict__ qlo,
    _Float16* __restrict__ khi, _Float16* __restrict__ klo,
    _Float16* __restrict__ vt)
{
    __shared__ float As[16][68];   // As[kk][row]  (transposed A tile)
    __shared__ float Bs[16][68];   // Bs[kk][col]
    __shared__ _Float16 Vts[64][72];
    const int tid = threadIdx.x;
    const int tr = tid >> 4, tc = tid & 15;
    const int bx = blockIdx.x, by = blockIdx.y;
    const int row0 = by << 6, col0 = bx << 6;
    const int ar = tid >> 2, ak = (tid & 3) << 2;
    const int bk = tid >> 4, bc = (tid & 15) << 2;
    float acc[4][4] = {};
    for (int kt = 0; kt < C_DIM; kt += 16) {
        const float4 a = *(const float4*)(X + (size_t)(row0 + ar) * C_DIM + kt + ak);
        const float4 b = *(const float4*)(W + (size_t)(kt + bk) * N_QKV + col0 + bc);
        __syncthreads();
        As[ak + 0][ar] = a.x; As[ak + 1][ar] = a.y;
        As[ak + 2][ar] = a.z; As[ak + 3][ar] = a.w;
        *(float4*)&Bs[bk][bc] = b;
        __syncthreads();
        #pragma unroll
        for (int kk = 0; kk < 16; ++kk) {
            float a_[4], b_[4];
            *(float4*)a_ = *(float4*)&As[kk][tr << 2];
            *(float4*)b_ = *(float4*)&Bs[kk][tc << 2];
            #pragma unroll
            for (int i = 0; i < 4; ++i)
                #pragma unroll
                for (int j = 0; j < 4; ++j)
                    acc[i][j] = fmaf(a_[i], b_[j], acc[i][j]);
        }
    }
    const int sec = bx / 12;
    const int h   = bx % 12;
    float o[4][4];
    #pragma unroll
    for (int i = 0; i < 4; ++i)
        #pragma unroll
        for (int j = 0; j < 4; ++j)
            o[i][j] = acc[i][j] + bias[col0 + (tc << 2) + j];

    if (sec < 2) {
        _Float16* hi = (sec == 0) ? qhi : khi;
        _Float16* lo = (sec == 0) ? qlo : klo;
        #pragma unroll
        for (int i = 0; i < 4; ++i) {
            float ss = o[i][0]*o[i][0] + o[i][1]*o[i][1]
                     + o[i][2]*o[i][2] + o[i][3]*o[i][3];
            #pragma unroll
            for (int m = 1; m < 16; m <<= 1) ss += __shfl_xor(ss, m, 16);
            const float invn = 1.0f / fmaxf(sqrtf(ss), 1e-12f);
            const int t = row0 + (tr << 2) + i;
            half4 hv, lv;
            #pragma unroll
            for (int j = 0; j < 4; ++j) {
                const float v = o[i][j] * invn;
                const _Float16 vh = (_Float16)v;
                hv[j] = vh;
                lv[j] = (_Float16)(v - (float)vh);
            }
            const size_t base = (size_t)h * HT + (size_t)t * HD + (tc << 2);
            *(half4*)(hi + base) = hv;
            *(half4*)(lo + base) = lv;
        }
    } else {
        // V: transpose 64x64 through LDS -> vt[h][dv][t]
        __syncthreads();
        #pragma unroll
        for (int i = 0; i < 4; ++i)
            #pragma unroll
            for (int j = 0; j < 4; ++j)
                Vts[(tc << 2) + j][(tr << 2) + i] = (_Float16)o[i][j];
        __syncthreads();
        const int dv = tid >> 2, sg = (tid & 3) << 4;
        const half8 a = *(const half8*)&Vts[dv][sg];
        const half8 b = *(const half8*)&Vts[dv][sg + 8];
        _Float16* dst = vt + (size_t)h * HT + (size_t)dv * T_SEQ + row0 + sg;
        *(half8*)dst       = a;
        *(half8*)(dst + 8) = b;
    }
}

// ---------------------------------------------------------------------------
// Fused attention, barrier-free. 256 thr / 4 waves; wave wv owns q-rows
// [wv*16, wv*16+16). Per 64-key tile:
//   S^T = K·Q^T via 3x split-f16 MFMA (hi*hi + hi*lo + lo*hi), fp32 acc
//   cumsum: in-lane 4-chain + 2 shfl_up over fg segments + per-kr carry
//   att *2^-5 -> f16 -> wave-private LDS rows -> A-frag for PV MFMA
//   V frags direct from global vt[h][dv][t]
// ---------------------------------------------------------------------------
__global__ __launch_bounds__(256, 3) void attn_kernel(
    const _Float16* __restrict__ qhi, const _Float16* __restrict__ qlo,
    const _Float16* __restrict__ khi, const _Float16* __restrict__ klo,
    const _Float16* __restrict__ vt,  _Float16* __restrict__ ylin)
{
    __shared__ _Float16 P2[64][72];
    const int tid = threadIdx.x;
    const int wv = tid >> 6, lane = tid & 63;
    const int fm = lane & 15, fg = lane >> 4;
    const int h = blockIdx.y, qt = blockIdx.x;
    const size_t hb = (size_t)h * HT;

    // preload Q B-frags (fixed for whole block): [plane][kc]
    const int q = qt * 64 + wv * 16 + fm;
    half8 qf[2][2];
    #pragma unroll
    for (int kc = 0; kc < 2; ++kc) {
        const size_t off = hb + (size_t)q * HD + kc * 32 + fg * 8;
        qf[0][kc] = *(const half8*)(qhi + off);
        qf[1][kc] = *(const half8*)(qlo + off);
    }

    f32x4 yacc[4];
    #pragma unroll
    for (int ct = 0; ct < 4; ++ct) yacc[ct] = (f32x4){0.f, 0.f, 0.f, 0.f};
    float carry = 0.0f;

    #pragma unroll 1
    for (int kt = 0; kt < T_SEQ / 64; ++kt) {
        const size_t kbase = hb + (size_t)kt * 64 * HD;
        // K A-frags: [kr][kc] hi and lo
        half8 ka[4][2], kl[4][2];
        #pragma unroll
        for (int kr = 0; kr < 4; ++kr)
            #pragma unroll
            for (int kc = 0; kc < 2; ++kc) {
                const size_t off = kbase + (size_t)(kr * 16 + fm) * HD + kc * 32 + fg * 8;
                ka[kr][kc] = *(const half8*)(khi + off);
                kl[kr][kc] = *(const half8*)(klo + off);
            }
        // V B-frags: [ct][kc]
        half8 vf[4][2];
        #pragma unroll
        for (int ct = 0; ct < 4; ++ct)
            #pragma unroll
            for (int kc = 0; kc < 2; ++kc)
                vf[ct][kc] = *(const half8*)(vt + hb + (size_t)(ct * 16 + fm) * T_SEQ
                                             + kt * 64 + kc * 32 + fg * 8);

        // S^T = K·Q^T  (split-f16, fp32 acc)
        f32x4 sacc[4];
        #pragma unroll
        for (int kr = 0; kr < 4; ++kr) sacc[kr] = (f32x4){0.f, 0.f, 0.f, 0.f};
        #pragma unroll
        for (int kr = 0; kr < 4; ++kr)
            #pragma unroll
            for (int kc = 0; kc < 2; ++kc) {
                sacc[kr] = __builtin_amdgcn_mfma_f32_16x16x32_f16(ka[kr][kc], qf[0][kc], sacc[kr], 0, 0, 0);
                sacc[kr] = __builtin_amdgcn_mfma_f32_16x16x32_f16(ka[kr][kc], qf[1][kc], sacc[kr], 0, 0, 0);
                sacc[kr] = __builtin_amdgcn_mfma_f32_16x16x32_f16(kl[kr][kc], qf[0][kc], sacc[kr], 0, 0, 0);
            }

        // scan + att, kr tiles sequential (16 keys each)
        #pragma unroll
        for (int kr = 0; kr < 4; ++kr) {
            const float s0 = sacc[kr][0], s1 = sacc[kr][1];
            const float s2 = sacc[kr][2], s3 = sacc[kr][3];
            const float p1 = s0 + s1, p2 = p1 + s2, p3 = p2 + s3;
            float x = p3;
            const float t1 = __shfl_up(x, 16, 64); if (fg >= 1) x += t1;
            const float t2 = __shfl_up(x, 32, 64); if (fg >= 2) x += t2;
            const float base = carry + (x - p3);
            carry += __shfl(x, 48 + fm, 64);   // tile total from fg=3 lane, same fm
            const float a0 = s0 * __builtin_amdgcn_rcpf(fmaxf(base + s0, 1e-6f));
            const float a1 = s1 * __builtin_amdgcn_rcpf(fmaxf(base + p1, 1e-6f));
            const float a2 = s2 * __builtin_amdgcn_rcpf(fmaxf(base + p2, 1e-6f));
            const float a3 = s3 * __builtin_amdgcn_rcpf(fmaxf(base + p3, 1e-6f));
            half4 pk = {(_Float16)(a0 * 0.03125f), (_Float16)(a1 * 0.03125f),
                        (_Float16)(a2 * 0.03125f), (_Float16)(a3 * 0.03125f)};
            *(half4*)&P2[wv * 16 + fm][kr * 16 + fg * 4] = pk;
        }

        // Y += att @ V
        #pragma unroll
        for (int kc = 0; kc < 2; ++kc) {
            const half8 af = *(const half8*)&P2[wv * 16 + fm][kc * 32 + fg * 8];
            #pragma unroll
            for (int ct = 0; ct < 4; ++ct)
                yacc[ct] = __builtin_amdgcn_mfma_f32_16x16x32_f16(af, vf[ct][kc], yacc[ct], 0, 0, 0);
        }
    }

    // epilogue: ylin f16 = y * 2^-12 (acc holds y*2^-5 -> scale 2^-7)
    #pragma unroll
    for (int ct = 0; ct < 4; ++ct)
        #pragma unroll
        for (int r = 0; r < 4; ++r) {
            const int t = qt * 64 + wv * 16 + fg * 4 + r;
            ylin[(size_t)t * C_DIM + h * HD + ct * 16 + fm] =
                (_Float16)(yacc[ct][r] * 0.0078125f);
        }
}

// ---------------------------------------------------------------------------
// Proj GEMM via f16 MFMA: ylin(f16, *2^-12)[4096,768] @ Wp[768,768] -> out fp32
// ---------------------------------------------------------------------------
__global__ __launch_bounds__(256) void gemm_proj_kernel(
    const _Float16* __restrict__ A, const float* __restrict__ W,
    const float* __restrict__ bias, float* __restrict__ out)
{
    __shared__ _Float16 As[64][72];   // [m][k]
    __shared__ _Float16 Bt[64][72];   // [n][k]
    typedef _Float16 half2v __attribute__((ext_vector_type(2)));
    const int tid = threadIdx.x;
    const int w = tid >> 6, lane = tid & 63;
    const int m = lane & 15, g = lane >> 4;
    const int row0 = blockIdx.x << 6, col0 = blockIdx.y << 6;
    const int ar = tid >> 3, ac8 = (tid & 7) << 3;
    const int bn0 = (tid & 15) << 2, bpv = tid >> 4;
    f32x4 acc[4];
    #pragma unroll
    for (int ct = 0; ct < 4; ++ct) acc[ct] = (f32x4){0.f, 0.f, 0.f, 0.f};

    for (int kt = 0; kt < C_DIM; kt += 64) {
        half8 av0 = *(const half8*)(A + (size_t)(row0 + ar)      * C_DIM + kt + ac8);
        half8 av1 = *(const half8*)(A + (size_t)(row0 + ar + 32) * C_DIM + kt + ac8);
        float4 w0[2], w1[2];
        #pragma unroll
        for (int i = 0; i < 2; ++i) {
            const int k = kt + 2 * (bpv + 16 * i);
            w0[i] = *(const float4*)(W + (size_t)k       * C_DIM + col0 + bn0);
            w1[i] = *(const float4*)(W + (size_t)(k + 1) * C_DIM + col0 + bn0);
        }
        __syncthreads();
        *(half8*)&As[ar][ac8]      = av0;
        *(half8*)&As[ar + 32][ac8] = av1;
        #pragma unroll
        for (int i = 0; i < 2; ++i) {
            const int p = bpv + 16 * i;
            const float a_[4] = {w0[i].x, w0[i].y, w0[i].z, w0[i].w};
            const float b_[4] = {w1[i].x, w1[i].y, w1[i].z, w1[i].w};
            #pragma unroll
            for (int u = 0; u < 4; ++u) {
                half2v pk = {(_Float16)a_[u], (_Float16)b_[u]};
                *(half2v*)&Bt[bn0 + u][2*p] = pk;
            }
        }
        __syncthreads();
        #pragma unroll
        for (int kc = 0; kc < 2; ++kc) {
            const half8 a = *(half8*)&As[w * 16 + m][kc * 32 + g * 8];
            #pragma unroll
            for (int ct = 0; ct < 4; ++ct) {
                const half8 b = *(half8*)&Bt[ct * 16 + m][kc * 32 + g * 8];
                acc[ct] = __builtin_amdgcn_mfma_f32_16x16x32_f16(a, b, acc[ct], 0, 0, 0);
            }
        }
    }
    #pragma unroll
    for (int ct = 0; ct < 4; ++ct)
        #pragma unroll
        for (int r = 0; r < 4; ++r) {
            const int t = row0 + w * 16 + g * 4 + r;
            const int n = col0 + ct * 16 + m;
            out[(size_t)t * C_DIM + n] = acc[ct][r] * 4096.0f + bias[n];
        }
}

extern "C" void kernel_launch(void* const* d_in, const int* in_sizes, int n_in,
                              void* d_out, int out_size, void* d_ws, size_t ws_size,
                              hipStream_t stream)
{
    const float* x      = (const float*)d_in[0];
    const float* w_attn = (const float*)d_in[1];
    const float* b_attn = (const float*)d_in[2];
    const float* w_proj = (const float*)d_in[3];
    const float* b_proj = (const float*)d_in[4];
    float* out = (float*)d_out;

    const size_t per = (size_t)H_NUM * HT;        // 3,145,728 f16 elems / plane
    _Float16* base = (_Float16*)d_ws;
    _Float16* qhi  = base;
    _Float16* qlo  = base + per;
    _Float16* khi  = base + 2 * per;
    _Float16* klo  = base + 3 * per;
    _Float16* vtp  = base + 4 * per;
    _Float16* ylin = base + 5 * per;              // total ~37.7 MB

    gemm_qkv_kernel<<<dim3(N_QKV / 64, T_SEQ / 64), 256, 0, stream>>>(
        x, w_attn, b_attn, qhi, qlo, khi, klo, vtp);
    attn_kernel<<<dim3(T_SEQ / 64, H_NUM), 256, 0, stream>>>(
        qhi, qlo, khi, klo, vtp, ylin);
    gemm_proj_kernel<<<dim3(T_SEQ / 64, C_DIM / 64), 256, 0, stream>>>(
        ylin, w_proj, b_proj, out);
}

// Round 4
// 360.691 us; speedup vs baseline: 3.0916x; 2.2019x over previous
//
#include <hip/hip_runtime.h>

#define T_SEQ 4096
#define H_NUM 12
#define HD    64
#define C_DIM 768
#define N_QKV 2304
#define HT    (T_SEQ * HD)   // per-head elements = 262144

typedef float    f32x4 __attribute__((ext_vector_type(4)));
typedef _Float16 half8 __attribute__((ext_vector_type(8)));
typedef _Float16 half4 __attribute__((ext_vector_type(4)));

// async global->LDS, 16B/lane, dest = wave-uniform base + lane*16
#define GLDS(gp, lp) __builtin_amdgcn_global_load_lds( \
    (const __attribute__((address_space(1))) void*)(gp), \
    (__attribute__((address_space(3))) void*)(lp), 16, 0, 0)

// ---------------------------------------------------------------------------
// split x (fp32) -> xhi + xlo (f16 planes)
// ---------------------------------------------------------------------------
__global__ __launch_bounds__(256) void split_x_kernel(
    const float* __restrict__ x, _Float16* __restrict__ xh,
    _Float16* __restrict__ xl, int n4)
{
    const int i = blockIdx.x * 256 + threadIdx.x;
    if (i >= n4) return;
    const float4 v = ((const float4*)x)[i];
    const float vv[4] = {v.x, v.y, v.z, v.w};
    half4 h, l;
    #pragma unroll
    for (int j = 0; j < 4; ++j) {
        const _Float16 hh = (_Float16)vv[j];
        h[j] = hh;
        l[j] = (_Float16)(vv[j] - (float)hh);
    }
    ((half4*)xh)[i] = h;
    ((half4*)xl)[i] = l;
}

// ---------------------------------------------------------------------------
// transpose+split w_attn [768][2304] -> wthi/wtlo [2304][768] (f16)
// ---------------------------------------------------------------------------
__global__ __launch_bounds__(256) void split_wt_kernel(
    const float* __restrict__ W, _Float16* __restrict__ wth,
    _Float16* __restrict__ wtl)
{
    __shared__ float Ws[64][65];
    const int tid = threadIdx.x;
    const int n0 = blockIdx.x * 64, k0 = blockIdx.y * 64;
    const int lr = tid >> 4, lc = (tid & 15) << 2;
    #pragma unroll
    for (int i = 0; i < 4; ++i) {
        const float4 v = *(const float4*)(W + (size_t)(k0 + lr + i * 16) * N_QKV + n0 + lc);
        Ws[lr + i * 16][lc + 0] = v.x; Ws[lr + i * 16][lc + 1] = v.y;
        Ws[lr + i * 16][lc + 2] = v.z; Ws[lr + i * 16][lc + 3] = v.w;
    }
    __syncthreads();
    const int n = tid >> 2, ks = (tid & 3) << 4;
    half8 h0, h1, l0, l1;
    #pragma unroll
    for (int j = 0; j < 8; ++j) {
        const float v = Ws[ks + j][n];
        const _Float16 hh = (_Float16)v;
        h0[j] = hh; l0[j] = (_Float16)(v - (float)hh);
    }
    #pragma unroll
    for (int j = 0; j < 8; ++j) {
        const float v = Ws[ks + 8 + j][n];
        const _Float16 hh = (_Float16)v;
        h1[j] = hh; l1[j] = (_Float16)(v - (float)hh);
    }
    const size_t dst = (size_t)(n0 + n) * C_DIM + k0 + ks;
    *(half8*)(wth + dst) = h0; *(half8*)(wth + dst + 8) = h1;
    *(half8*)(wtl + dst) = l0; *(half8*)(wtl + dst + 8) = l1;
}

// ---------------------------------------------------------------------------
// QKV GEMM via split-f16 MFMA: [4096,768]x[768,2304] in 3 terms
// (AhBh + AhBl + AlBh), fp32 acc. 128m x 64n tile, BK=64, 256 thr.
// LDS staged via global_load_lds with XOR chunk swizzle; epilogue fuses
// bias + l2norm + hi/lo split (q,k) or bias + V transpose (v).
// ---------------------------------------------------------------------------
__global__ __launch_bounds__(256) void gemm_qkv_kernel(
    const _Float16* __restrict__ xh, const _Float16* __restrict__ xl,
    const _Float16* __restrict__ wth, const _Float16* __restrict__ wtl,
    const float* __restrict__ bias,
    _Float16* __restrict__ qhi, _Float16* __restrict__ qlo,
    _Float16* __restrict__ khi, _Float16* __restrict__ klo,
    _Float16* __restrict__ vt)
{
    __shared__ __align__(16) _Float16 AH[128 * 64];
    __shared__ __align__(16) _Float16 AL[128 * 64];
    __shared__ __align__(16) _Float16 BH[64 * 64];
    __shared__ __align__(16) _Float16 BL[64 * 64];
    const int tid = threadIdx.x;
    const int wv = tid >> 6, lane = tid & 63;
    const int fm = lane & 15, fg = lane >> 4;
    const int lrow = lane >> 3;
    const int lcs  = (lane & 7) ^ (lrow & 7);   // swizzled source chunk
    const int bx = blockIdx.x;                  // n-tile (0..35)
    const int m0 = blockIdx.y * 128;

    auto dma_chunk = [&](int c) {
        const int kc0 = c * 64;
        #pragma unroll
        for (int i = 0; i < 12; ++i) {
            const int qidx = wv * 12 + i;
            if (qidx < 16) {
                const int rg = qidx;
                GLDS(xh + (size_t)(m0 + rg * 8 + lrow) * C_DIM + kc0 + lcs * 8, &AH[rg * 512]);
            } else if (qidx < 32) {
                const int rg = qidx - 16;
                GLDS(xl + (size_t)(m0 + rg * 8 + lrow) * C_DIM + kc0 + lcs * 8, &AL[rg * 512]);
            } else if (qidx < 40) {
                const int rg = qidx - 32;
                GLDS(wth + (size_t)(bx * 64 + rg * 8 + lrow) * C_DIM + kc0 + lcs * 8, &BH[rg * 512]);
            } else {
                const int rg = qidx - 40;
                GLDS(wtl + (size_t)(bx * 64 + rg * 8 + lrow) * C_DIM + kc0 + lcs * 8, &BL[rg * 512]);
            }
        }
    };

    f32x4 acc[2][4];
    #pragma unroll
    for (int mt = 0; mt < 2; ++mt)
        #pragma unroll
        for (int ct = 0; ct < 4; ++ct) acc[mt][ct] = (f32x4){0.f, 0.f, 0.f, 0.f};

    const int swz = fm & 7;
    dma_chunk(0);
    #pragma unroll 1
    for (int c = 0; c < C_DIM / 64; ++c) {
        __syncthreads();   // staged chunk c visible (drains DMA vmcnt)
        half8 ah[2][2], al[2][2], bh[4][2], bl[4][2];
        #pragma unroll
        for (int mt = 0; mt < 2; ++mt) {
            const int rb = (wv * 32 + mt * 16 + fm) * 64;
            #pragma unroll
            for (int kc = 0; kc < 2; ++kc) {
                const int cb = ((kc * 4 + fg) ^ swz) * 8;
                ah[mt][kc] = *(const half8*)&AH[rb + cb];
                al[mt][kc] = *(const half8*)&AL[rb + cb];
            }
        }
        #pragma unroll
        for (int ct = 0; ct < 4; ++ct) {
            const int rb = (ct * 16 + fm) * 64;
            #pragma unroll
            for (int kc = 0; kc < 2; ++kc) {
                const int cb = ((kc * 4 + fg) ^ swz) * 8;
                bh[ct][kc] = *(const half8*)&BH[rb + cb];
                bl[ct][kc] = *(const half8*)&BL[rb + cb];
            }
        }
        __syncthreads();   // all waves done reading staging
        if (c + 1 < C_DIM / 64) dma_chunk(c + 1);   // overlaps with MFMAs below
        #pragma unroll
        for (int mt = 0; mt < 2; ++mt)
            #pragma unroll
            for (int ct = 0; ct < 4; ++ct)
                #pragma unroll
                for (int kc = 0; kc < 2; ++kc) {
                    acc[mt][ct] = __builtin_amdgcn_mfma_f32_16x16x32_f16(ah[mt][kc], bh[ct][kc], acc[mt][ct], 0, 0, 0);
                    acc[mt][ct] = __builtin_amdgcn_mfma_f32_16x16x32_f16(ah[mt][kc], bl[ct][kc], acc[mt][ct], 0, 0, 0);
                    acc[mt][ct] = __builtin_amdgcn_mfma_f32_16x16x32_f16(al[mt][kc], bh[ct][kc], acc[mt][ct], 0, 0, 0);
                }
    }

    const int sec = bx / 12, h = bx % 12;
    const size_t hb = (size_t)h * HT;
    float bb[4];
    #pragma unroll
    for (int ct = 0; ct < 4; ++ct) bb[ct] = bias[bx * 64 + ct * 16 + fm];

    if (sec < 2) {
        _Float16* dh = (sec == 0) ? qhi : khi;
        _Float16* dl = (sec == 0) ? qlo : klo;
        #pragma unroll
        for (int mt = 0; mt < 2; ++mt)
            #pragma unroll
            for (int r = 0; r < 4; ++r) {
                float o[4];
                float ss = 0.f;
                #pragma unroll
                for (int ct = 0; ct < 4; ++ct) {
                    o[ct] = acc[mt][ct][r] + bb[ct];
                    ss += o[ct] * o[ct];
                }
                #pragma unroll
                for (int mk = 1; mk < 16; mk <<= 1) ss += __shfl_xor(ss, mk, 16);
                const float invn = 1.0f / fmaxf(sqrtf(ss), 1e-12f);
                const int t = m0 + wv * 32 + mt * 16 + fg * 4 + r;
                const size_t rb = hb + (size_t)t * HD;
                #pragma unroll
                for (int ct = 0; ct < 4; ++ct) {
                    const float v = o[ct] * invn;
                    const _Float16 vh = (_Float16)v;
                    dh[rb + ct * 16 + fm] = vh;
                    dl[rb + ct * 16 + fm] = (_Float16)(v - (float)vh);
                }
            }
    } else {
        #pragma unroll
        for (int mt = 0; mt < 2; ++mt) {
            const int t0 = m0 + wv * 32 + mt * 16 + fg * 4;
            #pragma unroll
            for (int ct = 0; ct < 4; ++ct) {
                half4 pk;
                #pragma unroll
                for (int r = 0; r < 4; ++r) pk[r] = (_Float16)(acc[mt][ct][r] + bb[ct]);
                *(half4*)(vt + hb + (size_t)(ct * 16 + fm) * T_SEQ + t0) = pk;
            }
        }
    }
}

// ---------------------------------------------------------------------------
// Fused attention. 256 thr / 4 waves; wave wv owns q-rows [wv*16, wv*16+16).
// K hi/lo + V staged in LDS via swizzled global_load_lds (single buffer,
// next-tile DMA issued after frag reads -> overlaps compute).
//   S^T = K.Q^T via 3x split-f16 MFMA; cumsum via 2x shfl_xor butterfly;
//   att*2^-5 -> f16 -> wave-private LDS -> A-frag for PV MFMA.
// ---------------------------------------------------------------------------
__global__ __launch_bounds__(256) void attn_kernel(
    const _Float16* __restrict__ qhi, const _Float16* __restrict__ qlo,
    const _Float16* __restrict__ khi, const _Float16* __restrict__ klo,
    const _Float16* __restrict__ vt,  _Float16* __restrict__ ylin)
{
    __shared__ __align__(16) _Float16 KH[64 * 64];
    __shared__ __align__(16) _Float16 KL[64 * 64];
    __shared__ __align__(16) _Float16 VS[64 * 64];
    __shared__ __align__(16) _Float16 P2[64][72];

    const int tid = threadIdx.x;
    const int wv = tid >> 6, lane = tid & 63;
    const int fm = lane & 15, fg = lane >> 4;
    const int lrow = lane >> 3;
    const int lcs  = (lane & 7) ^ (lrow & 7);
    const int h = blockIdx.y, qt = blockIdx.x;
    const size_t hb = (size_t)h * HT;

    // Q B-frags, fixed for whole block
    const int q = qt * 64 + wv * 16 + fm;
    half8 qf[2][2];
    #pragma unroll
    for (int kc = 0; kc < 2; ++kc) {
        const size_t off = hb + (size_t)q * HD + kc * 32 + fg * 8;
        qf[0][kc] = *(const half8*)(qhi + off);
        qf[1][kc] = *(const half8*)(qlo + off);
    }

    auto dma_tile = [&](int kt) {
        const size_t kb = hb + (size_t)kt * 64 * HD;
        const int vcol = kt * 64;
        #pragma unroll
        for (int i = 0; i < 6; ++i) {
            const int qidx = wv * 6 + i;
            const int rg = qidx & 7;
            if (qidx < 8) {
                GLDS(khi + kb + (size_t)(rg * 8 + lrow) * HD + lcs * 8, &KH[rg * 512]);
            } else if (qidx < 16) {
                GLDS(klo + kb + (size_t)(rg * 8 + lrow) * HD + lcs * 8, &KL[rg * 512]);
            } else {
                GLDS(vt + hb + (size_t)(rg * 8 + lrow) * T_SEQ + vcol + lcs * 8, &VS[rg * 512]);
            }
        }
    };

    f32x4 yacc[4];
    #pragma unroll
    for (int ct = 0; ct < 4; ++ct) yacc[ct] = (f32x4){0.f, 0.f, 0.f, 0.f};
    float carry = 0.0f;
    const int swz = fm & 7;

    dma_tile(0);
    #pragma unroll 1
    for (int kt = 0; kt < T_SEQ / 64; ++kt) {
        __syncthreads();   // staged tile kt visible (drains DMA vmcnt)
        half8 ka[4][2], kl[4][2], vf[4][2];
        #pragma unroll
        for (int kr = 0; kr < 4; ++kr) {
            const int rb = (kr * 16 + fm) * 64;
            #pragma unroll
            for (int kc = 0; kc < 2; ++kc) {
                const int cb = ((kc * 4 + fg) ^ swz) * 8;
                ka[kr][kc] = *(const half8*)&KH[rb + cb];
                kl[kr][kc] = *(const half8*)&KL[rb + cb];
            }
        }
        #pragma unroll
        for (int ct = 0; ct < 4; ++ct) {
            const int rb = (ct * 16 + fm) * 64;
            #pragma unroll
            for (int kc = 0; kc < 2; ++kc)
                vf[ct][kc] = *(const half8*)&VS[rb + (((kc * 4 + fg) ^ swz) * 8)];
        }
        __syncthreads();   // staging free; frags in registers
        if (kt + 1 < T_SEQ / 64) dma_tile(kt + 1);   // overlaps compute below

        // S^T = K.Q^T (split-f16, fp32 acc)
        f32x4 sacc[4];
        #pragma unroll
        for (int kr = 0; kr < 4; ++kr) sacc[kr] = (f32x4){0.f, 0.f, 0.f, 0.f};
        #pragma unroll
        for (int kr = 0; kr < 4; ++kr)
            #pragma unroll
            for (int kc = 0; kc < 2; ++kc) {
                sacc[kr] = __builtin_amdgcn_mfma_f32_16x16x32_f16(ka[kr][kc], qf[0][kc], sacc[kr], 0, 0, 0);
                sacc[kr] = __builtin_amdgcn_mfma_f32_16x16x32_f16(ka[kr][kc], qf[1][kc], sacc[kr], 0, 0, 0);
                sacc[kr] = __builtin_amdgcn_mfma_f32_16x16x32_f16(kl[kr][kc], qf[0][kc], sacc[kr], 0, 0, 0);
            }

        // scan: in-lane 4-chain + 2x shfl_xor butterfly (prefix + tile total)
        #pragma unroll
        for (int kr = 0; kr < 4; ++kr) {
            const float s0 = sacc[kr][0], s1 = sacc[kr][1];
            const float s2 = sacc[kr][2], s3 = sacc[kr][3];
            const float p1 = s0 + s1, p2 = p1 + s2, p3 = p2 + s3;
            const float u1 = __shfl_xor(p3, 16, 64);
            const float pair = p3 + u1;
            const float u2 = __shfl_xor(pair, 32, 64);
            const float tot16 = pair + u2;
            const float pref = ((fg & 1) ? u1 : 0.0f) + ((fg & 2) ? u2 : 0.0f);
            const float base = carry + pref;
            carry += tot16;
            const float a0 = s0 * __builtin_amdgcn_rcpf(fmaxf(base + s0, 1e-6f));
            const float a1 = s1 * __builtin_amdgcn_rcpf(fmaxf(base + p1, 1e-6f));
            const float a2 = s2 * __builtin_amdgcn_rcpf(fmaxf(base + p2, 1e-6f));
            const float a3 = s3 * __builtin_amdgcn_rcpf(fmaxf(base + p3, 1e-6f));
            half4 pk = {(_Float16)(a0 * 0.03125f), (_Float16)(a1 * 0.03125f),
                        (_Float16)(a2 * 0.03125f), (_Float16)(a3 * 0.03125f)};
            *(half4*)&P2[wv * 16 + fm][kr * 16 + fg * 4] = pk;
        }

        // Y += att @ V  (P2 round-trip is wave-private: no barrier)
        #pragma unroll
        for (int kc = 0; kc < 2; ++kc) {
            const half8 af = *(const half8*)&P2[wv * 16 + fm][kc * 32 + fg * 8];
            #pragma unroll
            for (int ct = 0; ct < 4; ++ct)
                yacc[ct] = __builtin_amdgcn_mfma_f32_16x16x32_f16(af, vf[ct][kc], yacc[ct], 0, 0, 0);
        }
    }

    // epilogue: ylin f16 = y * 2^-12 (acc holds y*2^-5 -> scale 2^-7)
    #pragma unroll
    for (int ct = 0; ct < 4; ++ct)
        #pragma unroll
        for (int r = 0; r < 4; ++r) {
            const int t = qt * 64 + wv * 16 + fg * 4 + r;
            ylin[(size_t)t * C_DIM + h * HD + ct * 16 + fm] =
                (_Float16)(yacc[ct][r] * 0.0078125f);
        }
}

// ---------------------------------------------------------------------------
// Proj GEMM via f16 MFMA: ylin(f16, *2^-12)[4096,768] @ Wp[768,768] -> out fp32
// ---------------------------------------------------------------------------
__global__ __launch_bounds__(256) void gemm_proj_kernel(
    const _Float16* __restrict__ A, const float* __restrict__ W,
    const float* __restrict__ bias, float* __restrict__ out)
{
    __shared__ _Float16 As[64][72];   // [m][k]
    __shared__ _Float16 Bt[64][72];   // [n][k]
    typedef _Float16 half2v __attribute__((ext_vector_type(2)));
    const int tid = threadIdx.x;
    const int w = tid >> 6, lane = tid & 63;
    const int m = lane & 15, g = lane >> 4;
    const int row0 = blockIdx.x << 6, col0 = blockIdx.y << 6;
    const int ar = tid >> 3, ac8 = (tid & 7) << 3;
    const int bn0 = (tid & 15) << 2, bpv = tid >> 4;
    f32x4 acc[4];
    #pragma unroll
    for (int ct = 0; ct < 4; ++ct) acc[ct] = (f32x4){0.f, 0.f, 0.f, 0.f};

    for (int kt = 0; kt < C_DIM; kt += 64) {
        half8 av0 = *(const half8*)(A + (size_t)(row0 + ar)      * C_DIM + kt + ac8);
        half8 av1 = *(const half8*)(A + (size_t)(row0 + ar + 32) * C_DIM + kt + ac8);
        float4 w0[2], w1[2];
        #pragma unroll
        for (int i = 0; i < 2; ++i) {
            const int k = kt + 2 * (bpv + 16 * i);
            w0[i] = *(const float4*)(W + (size_t)k       * C_DIM + col0 + bn0);
            w1[i] = *(const float4*)(W + (size_t)(k + 1) * C_DIM + col0 + bn0);
        }
        __syncthreads();
        *(half8*)&As[ar][ac8]      = av0;
        *(half8*)&As[ar + 32][ac8] = av1;
        #pragma unroll
        for (int i = 0; i < 2; ++i) {
            const int p = bpv + 16 * i;
            const float a_[4] = {w0[i].x, w0[i].y, w0[i].z, w0[i].w};
            const float b_[4] = {w1[i].x, w1[i].y, w1[i].z, w1[i].w};
            #pragma unroll
            for (int u = 0; u < 4; ++u) {
                half2v pk = {(_Float16)a_[u], (_Float16)b_[u]};
                *(half2v*)&Bt[bn0 + u][2 * p] = pk;
            }
        }
        __syncthreads();
        #pragma unroll
        for (int kc = 0; kc < 2; ++kc) {
            const half8 a = *(half8*)&As[w * 16 + m][kc * 32 + g * 8];
            #pragma unroll
            for (int ct = 0; ct < 4; ++ct) {
                const half8 b = *(half8*)&Bt[ct * 16 + m][kc * 32 + g * 8];
                acc[ct] = __builtin_amdgcn_mfma_f32_16x16x32_f16(a, b, acc[ct], 0, 0, 0);
            }
        }
    }
    #pragma unroll
    for (int ct = 0; ct < 4; ++ct)
        #pragma unroll
        for (int r = 0; r < 4; ++r) {
            const int t = row0 + w * 16 + g * 4 + r;
            const int n = col0 + ct * 16 + m;
            out[(size_t)t * C_DIM + n] = acc[ct][r] * 4096.0f + bias[n];
        }
}

extern "C" void kernel_launch(void* const* d_in, const int* in_sizes, int n_in,
                              void* d_out, int out_size, void* d_ws, size_t ws_size,
                              hipStream_t stream)
{
    const float* x      = (const float*)d_in[0];
    const float* w_attn = (const float*)d_in[1];
    const float* b_attn = (const float*)d_in[2];
    const float* w_proj = (const float*)d_in[3];
    const float* b_proj = (const float*)d_in[4];
    float* out = (float*)d_out;

    const size_t perQK = (size_t)H_NUM * HT;      // 3,145,728
    const size_t perX  = (size_t)T_SEQ * C_DIM;   // 3,145,728
    const size_t perW  = (size_t)N_QKV * C_DIM;   // 1,769,472
    _Float16* base = (_Float16*)d_ws;
    _Float16* xhi  = base;
    _Float16* xlo  = xhi + perX;
    _Float16* wthi = xlo + perX;
    _Float16* wtlo = wthi + perW;
    _Float16* qhi  = wtlo + perW;
    _Float16* qlo  = qhi + perQK;
    _Float16* khi  = qlo + perQK;
    _Float16* klo  = khi + perQK;
    _Float16* vtp  = klo + perQK;
    _Float16* ylin = xhi;                          // reuse: xhi dead after qkv

    split_x_kernel<<<(perX / 4 + 255) / 256, 256, 0, stream>>>(x, xhi, xlo, perX / 4);
    split_wt_kernel<<<dim3(N_QKV / 64, C_DIM / 64), 256, 0, stream>>>(w_attn, wthi, wtlo);
    gemm_qkv_kernel<<<dim3(N_QKV / 64, T_SEQ / 128), 256, 0, stream>>>(
        xhi, xlo, wthi, wtlo, b_attn, qhi, qlo, khi, klo, vtp);
    attn_kernel<<<dim3(T_SEQ / 64, H_NUM), 256, 0, stream>>>(
        qhi, qlo, khi, klo, vtp, ylin);
    gemm_proj_kernel<<<dim3(T_SEQ / 64, C_DIM / 64), 256, 0, stream>>>(
        ylin, w_proj, b_proj, out);
}